// Round 10
// baseline (90.373 us; speedup 1.0000x reference)
//
#include <hip/hip_runtime.h>
#include <hip/hip_bf16.h>
#include <math.h>

// ---- constants mirroring the reference ----
#define TWO_PI_D 6.283185307179586
constexpr int   NOFF  = 32768;
constexpr int   NSAMP = 128;
constexpr int   NRF   = 4;
constexpr int   NSTEP = NRF * NSAMP;   // 512
constexpr float DT    = 3.9e-05f;
constexpr double DTD  = 3.9e-05;
constexpr float R1A   = 1.0f / 1.3f;
constexpr float R2A   = 1.0f / 0.075f;
constexpr float R1B   = 1.0f;
constexpr float R2B   = 30.0f;
constexpr float KBv   = 200.0f;
constexpr float FBv   = 0.01f;
constexpr float KAv   = FBv * KBv;     // 2.0
constexpr float DWB   = 447.0f;

struct AccPhD { double a[8]; };        // [sim][rf_block] accumulated phase (f64)

// Per-(sim,step) EXACT RF rotation R = exp(W*DT): Rodrigues about in-plane
// axis n = (-cos ph, -sin ph, 0), angle th = w1*DT. 6 distinct coeffs.
// Stored as 8 floats: [r00,r01,r02,r12][r11,r22,0,0].
__global__ void rot_table_kernel(const float* __restrict__ amps,
                                 const float* __restrict__ phases,
                                 AccPhD acc, float4* __restrict__ rt4) {
    int tid = blockIdx.x * blockDim.x + threadIdx.x;   // 0..1023
    if (tid >= 2 * NSTEP) return;
    int sim = tid >> 9;
    int idx = tid & (NSTEP - 1);
    int r   = idx >> 7;
    double ph = -(double)phases[idx] - acc.a[sim * 4 + r];
    double w1 = TWO_PI_D * 42.577 * (double)amps[idx];
    double th = w1 * DTD;
    double sn = sin(th), cs = cos(th), Cc = 1.0 - cs;
    double nx = -cos(ph), ny = -sin(ph);
    float r00 = (float)(cs + nx * nx * Cc);
    float r01 = (float)(nx * ny * Cc);
    float r02 = (float)(ny * sn);
    float r12 = (float)(-nx * sn);
    float r11 = (float)(cs + ny * ny * Cc);
    float r22 = (float)cs;
    rt4[2 * tid]     = make_float4(r00, r01, r02, r12);
    rt4[2 * tid + 1] = make_float4(r11, r22, 0.0f, 0.0f);
}

__global__ void init_kernel(unsigned int* g) {
    if (threadIdx.x < 2) g[threadIdx.x] = 0u;
}

__global__ __launch_bounds__(256, 1) void bmc_kernel(
        const float* __restrict__ offsets,
        const float* __restrict__ m_init,
        const float* __restrict__ rt,
        unsigned int* __restrict__ gmax) {
    int tid = blockIdx.x * blockDim.x + threadIdx.x;   // 0..65535
    int sim = tid >> 15;
    int o   = tid & (NOFF - 1);

    const float TP  = (float)TWO_PI_D;
    float rf  = sim ? -200.0f : 200.0f;
    float off = offsets[o];
    float dwa = TP * (off - rf);
    float dwb = TP * ((off + DWB) - rf);

    // ---- one-time: Eh = exp(D~ * DT/2) (augmented 6x7, order-9 Taylor),
    //      then Ef = Eh*Eh (full step). D~ = [[D, b],[0,0]], D = drift. ----
    const float h     = 0.5f * DT;
    const float ca_h  = -(R2A + KAv) * h;
    const float cb_h  = -(R1A + KAv) * h;
    const float cc_h  = -(R2B + KBv) * h;
    const float cd_h  = -(R1B + KBv) * h;
    const float ka_h  = KAv * h, kb_h = KBv * h;
    const float dwa_h = dwa * h, dwb_h = dwb * h;
    const float b2_h  = R1A * h, b5_h = R1B * FBv * h;

    float Eh[6][7], U[6][7];
#pragma unroll
    for (int i = 0; i < 6; ++i)
#pragma unroll
        for (int j = 0; j < 7; ++j) {
            float v = (i == j) ? 1.0f : 0.0f;
            Eh[i][j] = v; U[i][j] = v;
        }
#pragma unroll
    for (int k = 1; k <= 9; ++k) {
        const float rk = 1.0f / (float)k;
        float N[6][7];
#pragma unroll
        for (int i = 0; i < 6; ++i) {
            N[i][0] = U[i][0] * ca_h  - U[i][1] * dwa_h + U[i][3] * ka_h;
            N[i][1] = U[i][0] * dwa_h + U[i][1] * ca_h  + U[i][4] * ka_h;
            N[i][2] = U[i][2] * cb_h  + U[i][5] * ka_h;
            N[i][3] = U[i][0] * kb_h  + U[i][3] * cc_h  - U[i][4] * dwb_h;
            N[i][4] = U[i][1] * kb_h  + U[i][3] * dwb_h + U[i][4] * cc_h;
            N[i][5] = U[i][2] * kb_h  + U[i][5] * cd_h;
            N[i][6] = U[i][2] * b2_h  + U[i][5] * b5_h;
        }
#pragma unroll
        for (int i = 0; i < 6; ++i)
#pragma unroll
            for (int j = 0; j < 7; ++j) {
                U[i][j] = N[i][j] * rk;
                Eh[i][j] += U[i][j];
            }
    }
    float Ef[6][7];
#pragma unroll
    for (int i = 0; i < 6; ++i)
#pragma unroll
        for (int j = 0; j < 7; ++j) {
            float s = (j == 6) ? Eh[i][6] : 0.0f;
#pragma unroll
            for (int k2 = 0; k2 < 6; ++k2) s += Eh[i][k2] * Eh[k2][j];
            Ef[i][j] = s;
        }

    // Named scalar copies of Ef (keeps everything in VGPRs, no indexed access)
    const float E00=Ef[0][0],E01=Ef[0][1],E02=Ef[0][2],E03=Ef[0][3],E04=Ef[0][4],E05=Ef[0][5],Q0=Ef[0][6];
    const float E10=Ef[1][0],E11=Ef[1][1],E12=Ef[1][2],E13=Ef[1][3],E14=Ef[1][4],E15=Ef[1][5],Q1=Ef[1][6];
    const float E20=Ef[2][0],E21=Ef[2][1],E22=Ef[2][2],E23=Ef[2][3],E24=Ef[2][4],E25=Ef[2][5],Q2=Ef[2][6];
    const float E30=Ef[3][0],E31=Ef[3][1],E32=Ef[3][2],E33=Ef[3][3],E34=Ef[3][4],E35=Ef[3][5],Q3=Ef[3][6];
    const float E40=Ef[4][0],E41=Ef[4][1],E42=Ef[4][2],E43=Ef[4][3],E44=Ef[4][4],E45=Ef[4][5],Q4=Ef[4][6];
    const float E50=Ef[5][0],E51=Ef[5][1],E52=Ef[5][2],E53=Ef[5][3],E54=Ef[5][4],E55=Ef[5][5],Q5=Ef[5][6];

    // ---- pre: m = Eh * [m_init; 1]  (enter the half-shifted Strang frame) ----
    float x0 = m_init[0], x1 = m_init[1], x2 = m_init[2];
    float x3 = m_init[3], x4 = m_init[4], x5 = m_init[5];
    float mi[6];
#pragma unroll
    for (int i = 0; i < 6; ++i)
        mi[i] = Eh[i][6] + Eh[i][0]*x0 + Eh[i][1]*x1 + Eh[i][2]*x2
                         + Eh[i][3]*x3 + Eh[i][4]*x4 + Eh[i][5]*x5;
    float m0 = mi[0], m1 = mi[1], m2 = mi[2], m3 = mi[3], m4 = mi[4], m5 = mi[5];
    float lmax = 0.0f;

    // ---- per step (SCALAR): m <- Ef * (R(s) * m) + q.
    // Rotation: 6 parallel depth-3 FMA chains (18 FMA).
    // Drift: 6 parallel serial-6-FMA rows seeded with q (36 FMA).
    // Width>=6 x 2cyc issue covers the ~4cyc scalar dep latency -> no stall.
#define FULL_STEP(ta, tb)                                                      \
    {                                                                          \
        const float r00 = (ta).x, r01 = (ta).y, r02 = (ta).z, r12 = (ta).w;    \
        const float r11 = (tb).x, r22 = (tb).y;                                \
        float xa = fmaf(r00, m0, fmaf(r01, m1,  r02 * m2));                    \
        float ya = fmaf(r01, m0, fmaf(r11, m1,  r12 * m2));                    \
        float za = fmaf(-r02, m0, fmaf(-r12, m1, r22 * m2));                   \
        float xb = fmaf(r00, m3, fmaf(r01, m4,  r02 * m5));                    \
        float yb = fmaf(r01, m3, fmaf(r11, m4,  r12 * m5));                    \
        float zb = fmaf(-r02, m3, fmaf(-r12, m4, r22 * m5));                   \
        m0 = fmaf(E05, zb, fmaf(E04, yb, fmaf(E03, xb, fmaf(E02, za, fmaf(E01, ya, fmaf(E00, xa, Q0)))))); \
        m1 = fmaf(E15, zb, fmaf(E14, yb, fmaf(E13, xb, fmaf(E12, za, fmaf(E11, ya, fmaf(E10, xa, Q1)))))); \
        m2 = fmaf(E25, zb, fmaf(E24, yb, fmaf(E23, xb, fmaf(E22, za, fmaf(E21, ya, fmaf(E20, xa, Q2)))))); \
        m3 = fmaf(E35, zb, fmaf(E34, yb, fmaf(E33, xb, fmaf(E32, za, fmaf(E31, ya, fmaf(E30, xa, Q3)))))); \
        m4 = fmaf(E45, zb, fmaf(E44, yb, fmaf(E43, xb, fmaf(E42, za, fmaf(E41, ya, fmaf(E40, xa, Q4)))))); \
        m5 = fmaf(E55, zb, fmaf(E54, yb, fmaf(E53, xb, fmaf(E52, za, fmaf(E51, ya, fmaf(E50, xa, Q5)))))); \
        lmax = fmaxf(lmax, fmaf(m0, m0, m1 * m1));                             \
    }

    const float4* __restrict__ rt4 = (const float4*)rt + (size_t)sim * NSTEP * 2;
    // A/B double-buffer, 8 steps (=16 float4) per iteration, no register copies.
    float4 a0 = rt4[0], a1 = rt4[1], a2 = rt4[2], a3 = rt4[3];
    float4 a4 = rt4[4], a5 = rt4[5], a6 = rt4[6], a7 = rt4[7];
    float4 b0 = rt4[8], b1 = rt4[9], b2 = rt4[10], b3 = rt4[11];
    float4 b4 = rt4[12], b5 = rt4[13], b6 = rt4[14], b7 = rt4[15];
#pragma unroll 1
    for (int j = 0; j < 63; ++j) {               // steps 0..503
        int nb = (j + 1) * 16;                   // 16 float4 consumed per iter
        FULL_STEP(a0, a1)                        // steps 8j .. 8j+3
        FULL_STEP(a2, a3)
        FULL_STEP(a4, a5)
        FULL_STEP(a6, a7)
        a0 = rt4[nb+0]; a1 = rt4[nb+1]; a2 = rt4[nb+2]; a3 = rt4[nb+3];
        a4 = rt4[nb+4]; a5 = rt4[nb+5]; a6 = rt4[nb+6]; a7 = rt4[nb+7];
        FULL_STEP(b0, b1)                        // steps 8j+4 .. 8j+7
        FULL_STEP(b2, b3)
        FULL_STEP(b4, b5)
        FULL_STEP(b6, b7)
        b0 = rt4[nb+8];  b1 = rt4[nb+9];  b2 = rt4[nb+10]; b3 = rt4[nb+11];
        b4 = rt4[nb+12]; b5 = rt4[nb+13]; b6 = rt4[nb+14]; b7 = rt4[nb+15];
    }
    // after loop: A = steps 504..507, B = steps 508..511
    FULL_STEP(a0, a1)
    FULL_STEP(a2, a3)
    FULL_STEP(a4, a5)
    FULL_STEP(a6, a7)
    FULL_STEP(b0, b1)
    FULL_STEP(b2, b3)
    FULL_STEP(b4, b5)
    // step 511: rotation, then HALF drift (exit the Strang frame exactly)
    {
        const float r00 = b6.x, r01 = b6.y, r02 = b6.z, r12 = b6.w;
        const float r11 = b7.x, r22 = b7.y;
        float xa = fmaf(r00, m0, fmaf(r01, m1,  r02 * m2));
        float ya = fmaf(r01, m0, fmaf(r11, m1,  r12 * m2));
        float za = fmaf(-r02, m0, fmaf(-r12, m1, r22 * m2));
        float xb = fmaf(r00, m3, fmaf(r01, m4,  r02 * m5));
        float yb = fmaf(r01, m3, fmaf(r11, m4,  r12 * m5));
        float zb = fmaf(-r02, m3, fmaf(-r12, m4, r22 * m5));
        float f0 = Eh[0][6] + Eh[0][0]*xa + Eh[0][1]*ya + Eh[0][2]*za
                            + Eh[0][3]*xb + Eh[0][4]*yb + Eh[0][5]*zb;
        float f1 = Eh[1][6] + Eh[1][0]*xa + Eh[1][1]*ya + Eh[1][2]*za
                            + Eh[1][3]*xb + Eh[1][4]*yb + Eh[1][5]*zb;
        lmax = fmaxf(lmax, fmaf(f0, f0, f1 * f1));
    }
#undef FULL_STEP

    // wave-64 max reduce, then one atomic per wave (sim uniform per wave)
    for (int d = 32; d >= 1; d >>= 1)
        lmax = fmaxf(lmax, __shfl_xor(lmax, d, 64));
    if ((threadIdx.x & 63) == 0)
        atomicMax(gmax + sim, __float_as_uint(lmax));   // all values >= 0

    (void)NSAMP;
}

__global__ void finalize_kernel(const unsigned int* __restrict__ gmax,
                                float* __restrict__ out) {
    int i = threadIdx.x;
    if (i < 2) out[i] = sqrtf(__uint_as_float(gmax[i]));   // float32 output
}

extern "C" void kernel_launch(void* const* d_in, const int* in_sizes, int n_in,
                              void* d_out, int out_size, void* d_ws, size_t ws_size,
                              hipStream_t stream) {
    const float* amps    = (const float*)d_in[0];   // (4,128)
    const float* phases  = (const float*)d_in[1];   // (4,128)
    const float* offsets = (const float*)d_in[2];   // (32768,)
    const float* m_init  = (const float*)d_in[3];   // (6,)
    float* out           = (float*)d_out;           // (2,) float32

    unsigned int* gmax = (unsigned int*)d_ws;                 // 2 slots
    float* rt = (float*)((char*)d_ws + 256);                  // 2*512*8 floats = 32 KB

    // Python-semantics accumulated phase per (sim, rf block), in f64
    AccPhD acc;
    for (int s = 0; s < 2; ++s) {
        double rfo  = s ? -200.0 : 200.0;
        double accp = 0.0;
        for (int r = 0; r < NRF; ++r) {
            acc.a[s * 4 + r] = accp;
            double pd = fmod(3.9e-05 * 128.0 * 360.0 * rfo, 360.0);
            if (pd < 0.0) pd += 360.0;      // Python % semantics
            accp += pd / 180.0 * M_PI;
        }
    }

    init_kernel<<<1, 64, 0, stream>>>(gmax);
    rot_table_kernel<<<4, 256, 0, stream>>>(amps, phases, acc, (float4*)rt);
    bmc_kernel<<<(2 * NOFF) / 256, 256, 0, stream>>>(offsets, m_init, rt, gmax);
    finalize_kernel<<<1, 64, 0, stream>>>(gmax, out);
}

// Round 11
// 79.571 us; speedup vs baseline: 1.1358x; 1.1358x over previous
//
#include <hip/hip_runtime.h>
#include <hip/hip_bf16.h>
#include <math.h>

// ---- constants mirroring the reference ----
#define TWO_PI_D 6.283185307179586
constexpr int   NOFF  = 32768;
constexpr int   NSAMP = 128;
constexpr int   NRF   = 4;
constexpr int   NSTEP = NRF * NSAMP;   // 512
constexpr float DT    = 3.9e-05f;
constexpr double DTD  = 3.9e-05;
constexpr float R1A   = 1.0f / 1.3f;
constexpr float R2A   = 1.0f / 0.075f;
constexpr float R1B   = 1.0f;
constexpr float R2B   = 30.0f;
constexpr float KBv   = 200.0f;
constexpr float FBv   = 0.01f;
constexpr float KAv   = FBv * KBv;     // 2.0
constexpr float DWB   = 447.0f;

typedef float f32x4v __attribute__((ext_vector_type(4)));

// Volatile global_load with literal offset; dest is an asm-defined register.
#define GLOAD4(dst, p, OFF) \
    asm volatile("global_load_dwordx4 %0, %1, off offset:" #OFF \
                 : "=v"(dst) : "v"(p))
// Counted-vmcnt wait that READS-WRITES the 8 destination regs: consumers of
// these values data-depend on this asm, so compute cannot hoist above it.
// vmcnt is in-order for VMEM (HW-verified), so vmcnt(8) = "oldest 8 done".
#define VWAIT8(N, a0,a1,a2,a3,a4,a5,a6,a7) \
    asm volatile("s_waitcnt vmcnt(" #N ")" \
                 : "+v"(a0), "+v"(a1), "+v"(a2), "+v"(a3), \
                   "+v"(a4), "+v"(a5), "+v"(a6), "+v"(a7))

struct AccPhD { double a[8]; };        // [sim][rf_block] accumulated phase (f64)

// Per-(sim,step) EXACT RF rotation R = exp(W*DT): Rodrigues about in-plane
// axis n = (-cos ph, -sin ph, 0), angle th = w1*DT. 6 distinct coeffs.
// Stored as 8 floats: [r00,r01,r02,r12][r11,r22,0,0].
__global__ void rot_table_kernel(const float* __restrict__ amps,
                                 const float* __restrict__ phases,
                                 AccPhD acc, float4* __restrict__ rt4) {
    int tid = blockIdx.x * blockDim.x + threadIdx.x;   // 0..1023
    if (tid >= 2 * NSTEP) return;
    int sim = tid >> 9;
    int idx = tid & (NSTEP - 1);
    int r   = idx >> 7;
    double ph = -(double)phases[idx] - acc.a[sim * 4 + r];
    double w1 = TWO_PI_D * 42.577 * (double)amps[idx];
    double th = w1 * DTD;
    double sn = sin(th), cs = cos(th), Cc = 1.0 - cs;
    double nx = -cos(ph), ny = -sin(ph);
    float r00 = (float)(cs + nx * nx * Cc);
    float r01 = (float)(nx * ny * Cc);
    float r02 = (float)(ny * sn);
    float r12 = (float)(-nx * sn);
    float r11 = (float)(cs + ny * ny * Cc);
    float r22 = (float)cs;
    rt4[2 * tid]     = make_float4(r00, r01, r02, r12);
    rt4[2 * tid + 1] = make_float4(r11, r22, 0.0f, 0.0f);
}

__global__ void init_kernel(unsigned int* g) {
    if (threadIdx.x < 2) g[threadIdx.x] = 0u;
}

__global__ __launch_bounds__(256)
__attribute__((amdgpu_waves_per_eu(1, 1)))   // grid = exactly 1 wave/SIMD:
void bmc_kernel(                             // let the allocator use max VGPRs
        const float* __restrict__ offsets,
        const float* __restrict__ m_init,
        const float* __restrict__ rt,
        unsigned int* __restrict__ gmax) {
    int tid = blockIdx.x * blockDim.x + threadIdx.x;   // 0..65535
    int sim = tid >> 15;
    int o   = tid & (NOFF - 1);

    const float TP  = (float)TWO_PI_D;
    float rf  = sim ? -200.0f : 200.0f;
    float off = offsets[o];
    float dwa = TP * (off - rf);
    float dwb = TP * ((off + DWB) - rf);

    // ---- one-time: Eh = exp(D~ * DT/2) (augmented 6x7, order-9 Taylor),
    //      then Ef = Eh*Eh (full step). D~ = [[D, b],[0,0]], D = drift. ----
    const float h     = 0.5f * DT;
    const float ca_h  = -(R2A + KAv) * h;
    const float cb_h  = -(R1A + KAv) * h;
    const float cc_h  = -(R2B + KBv) * h;
    const float cd_h  = -(R1B + KBv) * h;
    const float ka_h  = KAv * h, kb_h = KBv * h;
    const float dwa_h = dwa * h, dwb_h = dwb * h;
    const float b2_h  = R1A * h, b5_h = R1B * FBv * h;

    float Eh[6][7], U[6][7];
#pragma unroll
    for (int i = 0; i < 6; ++i)
#pragma unroll
        for (int j = 0; j < 7; ++j) {
            float v = (i == j) ? 1.0f : 0.0f;
            Eh[i][j] = v; U[i][j] = v;
        }
#pragma unroll
    for (int k = 1; k <= 9; ++k) {
        const float rk = 1.0f / (float)k;
        float N[6][7];
#pragma unroll
        for (int i = 0; i < 6; ++i) {
            N[i][0] = U[i][0] * ca_h  - U[i][1] * dwa_h + U[i][3] * ka_h;
            N[i][1] = U[i][0] * dwa_h + U[i][1] * ca_h  + U[i][4] * ka_h;
            N[i][2] = U[i][2] * cb_h  + U[i][5] * ka_h;
            N[i][3] = U[i][0] * kb_h  + U[i][3] * cc_h  - U[i][4] * dwb_h;
            N[i][4] = U[i][1] * kb_h  + U[i][3] * dwb_h + U[i][4] * cc_h;
            N[i][5] = U[i][2] * kb_h  + U[i][5] * cd_h;
            N[i][6] = U[i][2] * b2_h  + U[i][5] * b5_h;
        }
#pragma unroll
        for (int i = 0; i < 6; ++i)
#pragma unroll
            for (int j = 0; j < 7; ++j) {
                U[i][j] = N[i][j] * rk;
                Eh[i][j] += U[i][j];
            }
    }
    float Ef[6][7];
#pragma unroll
    for (int i = 0; i < 6; ++i)
#pragma unroll
        for (int j = 0; j < 7; ++j) {
            float s = (j == 6) ? Eh[i][6] : 0.0f;
#pragma unroll
            for (int k2 = 0; k2 < 6; ++k2) s += Eh[i][k2] * Eh[k2][j];
            Ef[i][j] = s;
        }

    // Named scalar copies of Ef (all-VGPR, no indexed access)
    const float E00=Ef[0][0],E01=Ef[0][1],E02=Ef[0][2],E03=Ef[0][3],E04=Ef[0][4],E05=Ef[0][5],Q0=Ef[0][6];
    const float E10=Ef[1][0],E11=Ef[1][1],E12=Ef[1][2],E13=Ef[1][3],E14=Ef[1][4],E15=Ef[1][5],Q1=Ef[1][6];
    const float E20=Ef[2][0],E21=Ef[2][1],E22=Ef[2][2],E23=Ef[2][3],E24=Ef[2][4],E25=Ef[2][5],Q2=Ef[2][6];
    const float E30=Ef[3][0],E31=Ef[3][1],E32=Ef[3][2],E33=Ef[3][3],E34=Ef[3][4],E35=Ef[3][5],Q3=Ef[3][6];
    const float E40=Ef[4][0],E41=Ef[4][1],E42=Ef[4][2],E43=Ef[4][3],E44=Ef[4][4],E45=Ef[4][5],Q4=Ef[4][6];
    const float E50=Ef[5][0],E51=Ef[5][1],E52=Ef[5][2],E53=Ef[5][3],E54=Ef[5][4],E55=Ef[5][5],Q5=Ef[5][6];

    // ---- pre: m = Eh * [m_init; 1]  (enter the half-shifted Strang frame).
    // Eh is dead after this point (final sample taken in half-frame too:
    // |Mxy| differs from the true frame by <= ~3e-4 relative, vs 1.8e-2 thr).
    float x0 = m_init[0], x1 = m_init[1], x2 = m_init[2];
    float x3 = m_init[3], x4 = m_init[4], x5 = m_init[5];
    float mi[6];
#pragma unroll
    for (int i = 0; i < 6; ++i)
        mi[i] = Eh[i][6] + Eh[i][0]*x0 + Eh[i][1]*x1 + Eh[i][2]*x2
                         + Eh[i][3]*x3 + Eh[i][4]*x4 + Eh[i][5]*x5;
    float m0 = mi[0], m1 = mi[1], m2 = mi[2], m3 = mi[3], m4 = mi[4], m5 = mi[5];
    float lmax = 0.0f;

    // ---- per step (SCALAR): m <- Ef * (R(s) * m) + q.
    // Rotation: 6 parallel depth-3 FMA chains (18 FMA).
    // Drift: 6 parallel serial-6-FMA rows seeded with q (36 FMA).
#define FULL_STEP(ta, tb)                                                      \
    {                                                                          \
        const float r00 = (ta)[0], r01 = (ta)[1], r02 = (ta)[2], r12 = (ta)[3];\
        const float r11 = (tb)[0], r22 = (tb)[1];                              \
        float xa = fmaf(r00, m0, fmaf(r01, m1,  r02 * m2));                    \
        float ya = fmaf(r01, m0, fmaf(r11, m1,  r12 * m2));                    \
        float za = fmaf(-r02, m0, fmaf(-r12, m1, r22 * m2));                   \
        float xb = fmaf(r00, m3, fmaf(r01, m4,  r02 * m5));                    \
        float yb = fmaf(r01, m3, fmaf(r11, m4,  r12 * m5));                    \
        float zb = fmaf(-r02, m3, fmaf(-r12, m4, r22 * m5));                   \
        m0 = fmaf(E05, zb, fmaf(E04, yb, fmaf(E03, xb, fmaf(E02, za, fmaf(E01, ya, fmaf(E00, xa, Q0)))))); \
        m1 = fmaf(E15, zb, fmaf(E14, yb, fmaf(E13, xb, fmaf(E12, za, fmaf(E11, ya, fmaf(E10, xa, Q1)))))); \
        m2 = fmaf(E25, zb, fmaf(E24, yb, fmaf(E23, xb, fmaf(E22, za, fmaf(E21, ya, fmaf(E20, xa, Q2)))))); \
        m3 = fmaf(E35, zb, fmaf(E34, yb, fmaf(E33, xb, fmaf(E32, za, fmaf(E31, ya, fmaf(E30, xa, Q3)))))); \
        m4 = fmaf(E45, zb, fmaf(E44, yb, fmaf(E43, xb, fmaf(E42, za, fmaf(E41, ya, fmaf(E40, xa, Q4)))))); \
        m5 = fmaf(E55, zb, fmaf(E54, yb, fmaf(E53, xb, fmaf(E52, za, fmaf(E51, ya, fmaf(E50, xa, Q5)))))); \
        lmax = fmaxf(lmax, fmaf(m0, m0, m1 * m1));                             \
    }

#define GLOAD_GROUP(B0,B1,B2,B3,B4,B5,B6,B7, p)  \
    GLOAD4(B0, p, 0);   GLOAD4(B1, p, 16);       \
    GLOAD4(B2, p, 32);  GLOAD4(B3, p, 48);       \
    GLOAD4(B4, p, 64);  GLOAD4(B5, p, 80);       \
    GLOAD4(B6, p, 96);  GLOAD4(B7, p, 112);

    // Table: 8 float4 per 4-step group; 128 groups. 2 buffers (A,B), each
    // buffer's loads get a full 4-step compute window before their wait.
    const float* rtg = rt + (size_t)sim * NSTEP * 8;   // per-sim table base
    f32x4v A0,A1,A2,A3,A4,A5,A6,A7, B0,B1,B2,B3,B4,B5,B6,B7;
    {
        const float* p0 = rtg;          // group 0
        const float* p1 = rtg + 32;     // group 1 (8 float4 = 32 floats)
        GLOAD_GROUP(A0,A1,A2,A3,A4,A5,A6,A7, p0)
        GLOAD_GROUP(B0,B1,B2,B3,B4,B5,B6,B7, p1)
    }
#pragma unroll 1
    for (int i = 0; i < 63; ++i) {               // consume groups 2i, 2i+1
        const float* pn0 = rtg + (size_t)(2 * i + 2) * 32;
        const float* pn1 = rtg + (size_t)(2 * i + 3) * 32;
        VWAIT8(8, A0,A1,A2,A3,A4,A5,A6,A7);      // group 2i ready; B in flight
        FULL_STEP(A0, A1)
        FULL_STEP(A2, A3)
        FULL_STEP(A4, A5)
        FULL_STEP(A6, A7)
        GLOAD_GROUP(A0,A1,A2,A3,A4,A5,A6,A7, pn0)   // prefetch group 2i+2
        VWAIT8(8, B0,B1,B2,B3,B4,B5,B6,B7);      // drains group 2i+1 (oldest 8)
        FULL_STEP(B0, B1)
        FULL_STEP(B2, B3)
        FULL_STEP(B4, B5)
        FULL_STEP(B6, B7)
        GLOAD_GROUP(B0,B1,B2,B3,B4,B5,B6,B7, pn1)   // prefetch group 2i+3
    }
    // tail: groups 126 (A), 127 (B) already in flight
    VWAIT8(8, A0,A1,A2,A3,A4,A5,A6,A7);
    FULL_STEP(A0, A1)
    FULL_STEP(A2, A3)
    FULL_STEP(A4, A5)
    FULL_STEP(A6, A7)
    VWAIT8(0, B0,B1,B2,B3,B4,B5,B6,B7);
    FULL_STEP(B0, B1)
    FULL_STEP(B2, B3)
    FULL_STEP(B4, B5)
    FULL_STEP(B6, B7)                            // step 511; half-frame sample
#undef FULL_STEP
#undef GLOAD_GROUP

    // wave-64 max reduce, then one atomic per wave (sim uniform per wave)
    for (int d = 32; d >= 1; d >>= 1)
        lmax = fmaxf(lmax, __shfl_xor(lmax, d, 64));
    if ((threadIdx.x & 63) == 0)
        atomicMax(gmax + sim, __float_as_uint(lmax));   // all values >= 0

    (void)NSAMP;
}

__global__ void finalize_kernel(const unsigned int* __restrict__ gmax,
                                float* __restrict__ out) {
    int i = threadIdx.x;
    if (i < 2) out[i] = sqrtf(__uint_as_float(gmax[i]));   // float32 output
}

extern "C" void kernel_launch(void* const* d_in, const int* in_sizes, int n_in,
                              void* d_out, int out_size, void* d_ws, size_t ws_size,
                              hipStream_t stream) {
    const float* amps    = (const float*)d_in[0];   // (4,128)
    const float* phases  = (const float*)d_in[1];   // (4,128)
    const float* offsets = (const float*)d_in[2];   // (32768,)
    const float* m_init  = (const float*)d_in[3];   // (6,)
    float* out           = (float*)d_out;           // (2,) float32

    unsigned int* gmax = (unsigned int*)d_ws;                 // 2 slots
    float* rt = (float*)((char*)d_ws + 256);                  // 2*512*8 floats = 32 KB

    // Python-semantics accumulated phase per (sim, rf block), in f64
    AccPhD acc;
    for (int s = 0; s < 2; ++s) {
        double rfo  = s ? -200.0 : 200.0;
        double accp = 0.0;
        for (int r = 0; r < NRF; ++r) {
            acc.a[s * 4 + r] = accp;
            double pd = fmod(3.9e-05 * 128.0 * 360.0 * rfo, 360.0);
            if (pd < 0.0) pd += 360.0;      // Python % semantics
            accp += pd / 180.0 * M_PI;
        }
    }

    init_kernel<<<1, 64, 0, stream>>>(gmax);
    rot_table_kernel<<<4, 256, 0, stream>>>(amps, phases, acc, (float4*)rt);
    bmc_kernel<<<(2 * NOFF) / 256, 256, 0, stream>>>(offsets, m_init, rt, gmax);
    finalize_kernel<<<1, 64, 0, stream>>>(gmax, out);
}